// Round 7
// baseline (518.313 us; speedup 1.0000x reference)
//
#include <hip/hip_runtime.h>

typedef short bf16x8 __attribute__((ext_vector_type(8)));
typedef float f32x4  __attribute__((ext_vector_type(4)));

#define SEQ   2048
#define HD    64
#define OUT0  (16 * SEQ * HD)     // weights offset in d_out (output comes first)
#define KB_OFF 0                  // ws layout (shorts): K bf16 [16][2048][64]
#define VT_OFF (16 * SEQ * HD)    // V^T bf16 [16][64][2048]
#define GT_OFF (2 * 16 * SEQ * HD) // skew table bf16 [2208][64]
#define GPAD  1056                // Gt row g holds E[g - GPAD] (zeros outside [0,1024))
#define GNR   2208
#define PSTR  72                  // per-wave P scratch row stride (shorts, 16B-aligned)

__device__ __forceinline__ short f2bf(float x) {
    unsigned u = __float_as_uint(x);
    unsigned r = u + 0x7fffu + ((u >> 16) & 1u);   // RNE
    return (short)(r >> 16);
}
__device__ __forceinline__ void cvt8(const float4& x, const float4& y, bf16x8& p) {
    p[0] = f2bf(x.x); p[1] = f2bf(x.y); p[2] = f2bf(x.z); p[3] = f2bf(x.w);
    p[4] = f2bf(y.x); p[5] = f2bf(y.y); p[6] = f2bf(y.z); p[7] = f2bf(y.w);
}

// ================= prep: build bf16 K, V^T, and padded skew table in ws =================
__global__ __launch_bounds__(256)
void prep(const float* __restrict__ kg, const float* __restrict__ vg,
          const float* __restrict__ eg, short* __restrict__ ws)
{
    const int b = blockIdx.x, t = threadIdx.x;
    short* Kb = ws + KB_OFF;
    short* Vt = ws + VT_OFF;
    short* Gt = ws + GT_OFF;
    if (b < 512) {
        // V transpose: one 64-key x 64-dim tile per block -> Vt[bh][d][key]
        __shared__ short tile[64 * 72];
        const int bh = b >> 5, kb = b & 31;
        const int r = t >> 2, cg = t & 3;
        const float4* src = (const float4*)(vg + ((size_t)(bh * SEQ + kb * 64 + r)) * HD + cg * 16);
        bf16x8 p0, p1;
        cvt8(src[0], src[1], p0);
        cvt8(src[2], src[3], p1);
        *(bf16x8*)&tile[r * 72 + cg * 16]     = p0;
        *(bf16x8*)&tile[r * 72 + cg * 16 + 8] = p1;
        __syncthreads();
        const int d = t >> 2, kq = t & 3;
#pragma unroll
        for (int u = 0; u < 2; ++u) {
            bf16x8 q;
#pragma unroll
            for (int x = 0; x < 8; ++x) q[x] = tile[(kq * 16 + u * 8 + x) * 72 + d];
            *(bf16x8*)&Vt[((size_t)(bh * 64 + d)) * SEQ + kb * 64 + kq * 16 + u * 8] = q;
        }
    } else if (b < 768) {
        // K f32 -> bf16 flat copy: 256 blocks x 256 thr x 32 shorts
        const int idx = (b - 512) * 256 + t;
        const float4* src = (const float4*)kg + (size_t)idx * 8;
        short* dst = Kb + (size_t)idx * 32;
#pragma unroll
        for (int u = 0; u < 4; ++u) {
            bf16x8 p; cvt8(src[2 * u], src[2 * u + 1], p);
            *(bf16x8*)&dst[u * 8] = p;
        }
    } else {
        // skew table: Gt[g][d] = E[g-GPAD][d] or 0
        for (int i = (b - 768) * 256 + t; i < GNR * HD; i += 64 * 256) {
            const int g = i >> 6, d = i & 63;
            const int e = g - GPAD;
            Gt[i] = (e >= 0 && e < 1024) ? f2bf(eg[(size_t)e * HD + d]) : (short)0;
        }
    }
}

// S(16q x 64j for one wave) = Q@K^T + skewed rel, fragments straight from L2/L3.
// tc tile dt covers local skew col x = dt*16 + c  (Gt row = grow0 - dt*16, grow0 = 2142 + j0 - iw - c).
// Gather T[rl][rl+63-jl] via partner shuffle: cp=(rl+63-c)&15 (involution); sender
// provides tc[((rl+63-cp)>=64 ? 4 : 3) - ct][rg].   [verified R1/R2]
__device__ __forceinline__ void compute_sc(const bf16x8* aq, const short* __restrict__ Kb,
                                           const short* __restrict__ Gt,
                                           int j0, int iw, int qd, int c, int lane,
                                           f32x4* sc, bool diag, int dloc)
{
    f32x4 tc[5];
    const f32x4 zz = {0.f, 0.f, 0.f, 0.f};
#pragma unroll
    for (int ct = 0; ct < 4; ++ct) sc[ct] = zz;
#pragma unroll
    for (int dt = 0; dt < 5; ++dt) tc[dt] = zz;
    const short* kbase = Kb + ((size_t)(j0 + c)) * HD + qd * 8;
    const short* gbase = Gt + ((size_t)(2142 + j0 - iw - c)) * HD + qd * 8;
#pragma unroll
    for (int s = 0; s < 2; ++s) {
        bf16x8 a = aq[s];
#pragma unroll
        for (int ct = 0; ct < 4; ++ct) {
            bf16x8 b = *(const bf16x8*)&kbase[(ct * 16) * HD + s * 32];
            sc[ct] = __builtin_amdgcn_mfma_f32_16x16x32_bf16(a, b, sc[ct], 0, 0, 0);
        }
#pragma unroll
        for (int dt = 0; dt < 5; ++dt) {
            bf16x8 g = *(const bf16x8*)&gbase[-(dt * 16) * HD + s * 32];
            tc[dt] = __builtin_amdgcn_mfma_f32_16x16x32_bf16(a, g, tc[dt], 0, 0, 0);
        }
    }
#pragma unroll
    for (int rg = 0; rg < 4; ++rg) {
        const int rl  = qd * 4 + rg;
        const int cp  = (rl + 63 - c) & 15;
        const int src = (lane & 48) | cp;
        const bool hi = (rl + 63 - cp) >= 64;
#pragma unroll
        for (int ct = 0; ct < 4; ++ct) {
            float vs = hi ? tc[4 - ct][rg] : tc[3 - ct][rg];
            float tr = __shfl(vs, src, 64);
            float sval = sc[ct][rg] + tr;
            if (diag && (ct * 16 + c > dloc + rl)) sval = -3.0e38f;  // causal (diag tile only)
            sc[ct][rg] = sval;
        }
    }
}

// ================= main kernel: zero block barriers in the k-loops =================
__global__ __launch_bounds__(256, 2)
void relattn(const float* __restrict__ qg, const short* __restrict__ ws,
             float* __restrict__ outp)
{
    __shared__ short Ps[4 * 16 * PSTR];   // per-wave P scratch (wave-local, no barriers)

    const int tid  = threadIdx.x;
    const int wv   = tid >> 6;
    const int lane = tid & 63;
    const int qd   = lane >> 4;
    const int c    = lane & 15;

    const int bh = blockIdx.x & 15;
    const int u  = blockIdx.x >> 4;
    const int qt = (u < 16) ? (31 - u) : (u - 16);   // heavy-first pairing
    const int i0 = qt * 64;
    const int iw = i0 + wv * 16;                     // this wave's first q-row

    const short* Kb = ws + KB_OFF + (size_t)bh * SEQ * HD;
    const short* Vt = ws + VT_OFF + (size_t)bh * 64 * SEQ;
    const short* Gt = ws + GT_OFF;
    float* Wg = outp + OUT0;

    // ---- zero-fill the fully-masked column region of weights ----
    {
        const int z0v = (qt + 1) * 16;    // first float4 column
        for (int r = 0; r < 64; ++r) {
            float4* dst = (float4*)(Wg + ((size_t)(bh * SEQ + i0 + r)) * SEQ);
            for (int jv = z0v + tid; jv < SEQ / 4; jv += 256)
                dst[jv] = make_float4(0.f, 0.f, 0.f, 0.f);
        }
    }

    // ---- Q A-fragments: convert directly from global f32 ----
    bf16x8 aq[2];
    {
        const float* qrow = qg + ((size_t)(bh * SEQ + iw + c)) * HD;
#pragma unroll
        for (int s = 0; s < 2; ++s) {
            float4 x = *(const float4*)(qrow + s * 32 + qd * 8);
            float4 y = *(const float4*)(qrow + s * 32 + qd * 8 + 4);
            cvt8(x, y, aq[s]);
        }
    }

    // =================== PASS 1: row sum-exp (wave-autonomous) ===================
    // q pre-scaled by 1/sqrt(d): |S| <~ 10 -> exp needs no max shift.
    float lrun[4];
#pragma unroll
    for (int rg = 0; rg < 4; ++rg) lrun[rg] = 0.f;
    for (int kt = 0; kt <= qt; ++kt) {
        f32x4 sc[4];
        compute_sc(aq, Kb, Gt, kt * 64, iw, qd, c, lane, sc, kt == qt, wv * 16);
#pragma unroll
        for (int rg = 0; rg < 4; ++rg)
            lrun[rg] += (__expf(sc[0][rg]) + __expf(sc[1][rg]))
                      + (__expf(sc[2][rg]) + __expf(sc[3][rg]));
    }
    // intra-wave reduce across the 16 c-lanes; store 1/l
#pragma unroll
    for (int rg = 0; rg < 4; ++rg) {
        float ss = lrun[rg];
        ss += __shfl_xor(ss, 1);
        ss += __shfl_xor(ss, 2);
        ss += __shfl_xor(ss, 4);
        ss += __shfl_xor(ss, 8);
        lrun[rg] = 1.0f / ss;
    }

    // =================== PASS 2: write normalized W, accumulate O ===================
    f32x4 ob[4];
    {
        const f32x4 zz = {0.f, 0.f, 0.f, 0.f};
#pragma unroll
        for (int dt = 0; dt < 4; ++dt) ob[dt] = zz;
    }
    short* Pw = &Ps[wv * 16 * PSTR];
    for (int kt = 0; kt <= qt; ++kt) {
        const int j0 = kt * 64;
        f32x4 sc[4];
        compute_sc(aq, Kb, Gt, j0, iw, qd, c, lane, sc, kt == qt, wv * 16);

        // W = exp(S)/l -> global weights + wave-local P (bf16, normalized)
#pragma unroll
        for (int rg = 0; rg < 4; ++rg) {
            const int rl = qd * 4 + rg;
            float* wrow = Wg + ((size_t)(bh * SEQ + iw + rl)) * SEQ + j0;
#pragma unroll
            for (int ct = 0; ct < 4; ++ct) {
                const float w = __expf(sc[ct][rg]) * lrun[rg];
                wrow[ct * 16 + c] = w;
                Pw[rl * PSTR + ct * 16 + c] = f2bf(w);
            }
        }

        // O += P(16x64) @ V(64x64), V^T fragments straight from L2/L3
#pragma unroll
        for (int s = 0; s < 2; ++s) {
            bf16x8 ap = *(const bf16x8*)&Pw[c * PSTR + s * 32 + qd * 8];
#pragma unroll
            for (int dt = 0; dt < 4; ++dt) {
                bf16x8 bv = *(const bf16x8*)&Vt[((size_t)(dt * 16 + c)) * SEQ + j0 + s * 32 + qd * 8];
                ob[dt] = __builtin_amdgcn_mfma_f32_16x16x32_bf16(ap, bv, ob[dt], 0, 0, 0);
            }
        }
    }

    // ---- write O (normalized, since P was normalized) ----
#pragma unroll
    for (int dt = 0; dt < 4; ++dt)
#pragma unroll
        for (int rg = 0; rg < 4; ++rg)
            outp[((size_t)(bh * SEQ + iw + qd * 4 + rg)) * HD + dt * 16 + c] = ob[dt][rg];
}

extern "C" void kernel_launch(void* const* d_in, const int* in_sizes, int n_in,
                              void* d_out, int out_size, void* d_ws, size_t ws_size,
                              hipStream_t stream) {
    const float* q = (const float*)d_in[0];
    const float* k = (const float*)d_in[1];
    const float* v = (const float*)d_in[2];
    const float* e = (const float*)d_in[3];
    // d_in[4] (mask) unused: causality computed from indices
    float* out = (float*)d_out;
    short* ws = (short*)d_ws;   // needs ~8.7 MB
    hipLaunchKernelGGL(prep,    dim3(832), dim3(256), 0, stream, k, v, e, ws);
    hipLaunchKernelGGL(relattn, dim3(512), dim3(256), 0, stream, q, ws, out);
}